// Round 5
// baseline (585.395 us; speedup 1.0000x reference)
//
#include <hip/hip_runtime.h>
#include <cstdint>

typedef __fp16 f16x8 __attribute__((ext_vector_type(8)));
typedef __fp16 f16x4 __attribute__((ext_vector_type(4)));
typedef float  f32x4 __attribute__((ext_vector_type(4)));

static constexpr int NDIM = 1024;  // N = H*W = C = KC = VC

// ---------------- workspace layout (bytes) ----------------
static constexpr long long OFF_W     = 0;
static constexpr long long OFF_BIAS  = 6291456;
static constexpr long long OFF_XT    = 6303744;
static constexpr long long OFF_S     = 0;
static constexpr long long OFF_QKV   = 134217728;
static constexpr long long OFF_STATS = OFF_QKV + 2097152;  // over k[0]
// total required: OFF_QKV + 32*3072*1024*2 = 335,544,320 bytes

__device__ __forceinline__ void async16(__fp16* lds, const __fp16* g) {
  __builtin_amdgcn_global_load_lds(
      (const __attribute__((address_space(1))) void*)g,
      (__attribute__((address_space(3))) void*)lds, 16, 0, 0);
}

// ---------------- small prep kernels ----------------
__global__ __launch_bounds__(256) void cast_w(const float* __restrict__ Wq,
                                              const float* __restrict__ Wk,
                                              const float* __restrict__ Wv,
                                              __fp16* __restrict__ W3) {
  const int i = blockIdx.x * 256 + threadIdx.x;
  const int which = i >> 18;
  const int j = i & 262143;
  const float* src = which == 0 ? Wq : (which == 1 ? Wk : Wv);
  const float4 v = ((const float4*)src)[j];
  f16x4 o = {(__fp16)v.x, (__fp16)v.y, (__fp16)v.z, (__fp16)v.w};
  ((f16x4*)W3)[i] = o;
}

__global__ __launch_bounds__(256) void pack_bias(const float* __restrict__ bq,
                                                 const float* __restrict__ bk,
                                                 const float* __restrict__ bv,
                                                 float* __restrict__ b3) {
  const int i = blockIdx.x * 256 + threadIdx.x;
  if (i < 1024) b3[i] = bq[i];
  else if (i < 2048) b3[i] = bk[i - 1024];
  else if (i < 3072) b3[i] = bv[i - 2048];
}

__global__ __launch_bounds__(256) void transpose_cast_x(const float* __restrict__ x,
                                                        __fp16* __restrict__ xT) {
  __shared__ float t[32][33];
  const int b = blockIdx.z;
  const int n0 = blockIdx.x * 32, c0 = blockIdx.y * 32;
  const float* xb = x + (long long)b * NDIM * NDIM;
  __fp16* ob = xT + (long long)b * NDIM * NDIM;
  const int tx = threadIdx.x & 31, ty = threadIdx.x >> 5;
#pragma unroll
  for (int i = ty; i < 32; i += 8)
    t[i][tx] = xb[(long long)(c0 + i) * NDIM + n0 + tx];
  __syncthreads();
#pragma unroll
  for (int i = ty; i < 32; i += 8)
    ob[(long long)(n0 + i) * NDIM + c0 + tx] = (__fp16)t[tx][i];
}

// ------------- 256x256 BK=64 8-phase gemm_bt (A[M][K] * B^T[N][K]) -------------
// Waves 4M x 2N (wave tile 64x128): each wave reads only A-half (wm>>1) and
// B-half (wn). LDS: A/B [2 buf][256 rows][64 cols] fp16, 16B-slot swizzle
// slot' = slot ^ (row&7) (both-sides: pre-swizzled gload source + swizzled read).
// Per K-tile: 4 phases {ds_read; stage unit(s) of tile t+1; barrier;
// lgkmcnt(0); setprio(1); 16 MFMA; setprio(0); barrier}. Stage units:
// P1: Ah0+Bh0, P2: Ah1+Bh1 (2 async16 each). Tile-seam wait: per-wave-class
// counted vmcnt (4/2/0) -- each wave waits only for the halves it reads.

#define LDA(c, mf, ks) \
  (*(const f16x8*)&As[(c)*16384 + aRowBase + (mf)*1024 + ((ks) ? ac1 : ac0)])
#define LDB_(c, nf, ks) \
  (*(const f16x8*)&Bs[(c)*16384 + bRowBase + (nf)*1024 + ((ks) ? ac1 : ac0)])

#define STAGE_AH(dst, h, kk)                                                          \
  async16(&As[(dst)*16384 + (h)*8192 + tid*8],                                        \
          A + (long long)(m0 + (h)*128 + sRow) * 1024 + (kk) + sCol);                 \
  async16(&As[(dst)*16384 + (h)*8192 + 4096 + tid*8],                                 \
          A + (long long)(m0 + (h)*128 + 64 + sRow) * 1024 + (kk) + sCol);

#define STAGE_BH(dst, h, kk)                                                          \
  async16(&Bs[(dst)*16384 + (h)*8192 + tid*8],                                        \
          Bp + (long long)(n0 + (h)*128 + sRow) * 1024 + (kk) + sCol);                \
  async16(&Bs[(dst)*16384 + (h)*8192 + 4096 + tid*8],                                 \
          Bp + (long long)(n0 + (h)*128 + 64 + sRow) * 1024 + (kk) + sCol);

#define MFMA_PH(nfp)                                                                  \
  asm volatile("s_waitcnt lgkmcnt(0)" ::: "memory");                                  \
  __builtin_amdgcn_sched_barrier(0);                                                  \
  __builtin_amdgcn_s_setprio(1);                                                      \
  _Pragma("unroll")                                                                   \
  for (int mq = 0; mq < 4; ++mq) {                                                    \
    acc[mq][(nfp)]     = __builtin_amdgcn_mfma_f32_16x16x32_f16(af[mq][0], bf[0][0], acc[mq][(nfp)],     0, 0, 0); \
    acc[mq][(nfp)]     = __builtin_amdgcn_mfma_f32_16x16x32_f16(af[mq][1], bf[0][1], acc[mq][(nfp)],     0, 0, 0); \
    acc[mq][(nfp) + 1] = __builtin_amdgcn_mfma_f32_16x16x32_f16(af[mq][0], bf[1][0], acc[mq][(nfp) + 1], 0, 0, 0); \
    acc[mq][(nfp) + 1] = __builtin_amdgcn_mfma_f32_16x16x32_f16(af[mq][1], bf[1][1], acc[mq][(nfp) + 1], 0, 0, 0); \
  }                                                                                   \
  __builtin_amdgcn_s_setprio(0);                                                      \
  __builtin_amdgcn_sched_barrier(0);

#define WAIT_CLASS                                                                    \
  if (cls == 0)      asm volatile("s_waitcnt vmcnt(4)" ::: "memory");                 \
  else if (cls == 1) asm volatile("s_waitcnt vmcnt(2)" ::: "memory");                 \
  else               asm volatile("s_waitcnt vmcnt(0)" ::: "memory");

#define TILE(c, knext)                                                                \
  /* P1 */                                                                            \
  _Pragma("unroll")                                                                   \
  for (int mq = 0; mq < 4; ++mq) { af[mq][0] = LDA(c, mq, 0); af[mq][1] = LDA(c, mq, 1); } \
  bf[0][0] = LDB_(c, 0, 0); bf[0][1] = LDB_(c, 0, 1);                                 \
  bf[1][0] = LDB_(c, 1, 0); bf[1][1] = LDB_(c, 1, 1);                                 \
  STAGE_AH((c) ^ 1, 0, knext)                                                         \
  STAGE_BH((c) ^ 1, 0, knext)                                                         \
  __builtin_amdgcn_s_barrier();                                                       \
  MFMA_PH(0)                                                                          \
  __builtin_amdgcn_s_barrier();                                                       \
  /* P2 */                                                                            \
  bf[0][0] = LDB_(c, 2, 0); bf[0][1] = LDB_(c, 2, 1);                                 \
  bf[1][0] = LDB_(c, 3, 0); bf[1][1] = LDB_(c, 3, 1);                                 \
  STAGE_AH((c) ^ 1, 1, knext)                                                         \
  STAGE_BH((c) ^ 1, 1, knext)                                                         \
  __builtin_amdgcn_s_barrier();                                                       \
  MFMA_PH(2)                                                                          \
  __builtin_amdgcn_s_barrier();                                                       \
  /* P3 */                                                                            \
  bf[0][0] = LDB_(c, 4, 0); bf[0][1] = LDB_(c, 4, 1);                                 \
  bf[1][0] = LDB_(c, 5, 0); bf[1][1] = LDB_(c, 5, 1);                                 \
  __builtin_amdgcn_s_barrier();                                                       \
  MFMA_PH(4)                                                                          \
  __builtin_amdgcn_s_barrier();                                                       \
  /* P4 */                                                                            \
  bf[0][0] = LDB_(c, 6, 0); bf[0][1] = LDB_(c, 6, 1);                                 \
  bf[1][0] = LDB_(c, 7, 0); bf[1][1] = LDB_(c, 7, 1);                                 \
  __builtin_amdgcn_s_barrier();                                                       \
  MFMA_PH(6)                                                                          \
  WAIT_CLASS                                                                          \
  __builtin_amdgcn_s_barrier();

template <int EPI>
__global__ __launch_bounds__(512, 2)
void gemm256(const __fp16* __restrict__ Ag, const __fp16* __restrict__ Bg,
             void* __restrict__ Cout, const float* __restrict__ bias,
             const float* __restrict__ X, const float* __restrict__ gamma,
             long long sA, long long sB, long long sC) {
  __shared__ alignas(16) __fp16 As[2 * 16384];
  __shared__ alignas(16) __fp16 Bs[2 * 16384];

  const int tid  = threadIdx.x;
  const int wid  = tid >> 6, lane = tid & 63;
  const int wm   = wid >> 1, wn = wid & 1;       // 4M x 2N
  const int g    = lane >> 4, r = lane & 15;

  // chunked XCD swizzle (bijective: nwg % 8 == 0) + batch-inner decode
  const int nwg = gridDim.x;
  const int bid = blockIdx.x;
  const int swz = (bid & 7) * (nwg >> 3) + (bid >> 3);
  const int bx = swz & 3, bz = (swz >> 2) & 31, by = swz >> 7;
  const int b = bz, m0 = by * 256, n0 = bx * 256;

  const __fp16* A  = Ag + (long long)b * sA;
  const __fp16* Bp = Bg + (long long)b * sB;

  // staging source pre-swizzle (LDS dest linear): within a 64-row sub-block,
  // row = tid>>3, slot = tid&7 holds source chunk (tid&7) ^ (row&7).
  const int sRow = tid >> 3;
  const int sCol = ((tid & 7) ^ ((tid >> 3) & 7)) * 8;

  // fragment reads: k-chunk slot s = ks*4+g of row R lives at slot s ^ (R&7),
  // R&7 == r&7 for all fragments (rows are multiples of 16 plus r).
  const int ac0 = ((g) ^ (r & 7)) * 8;
  const int ac1 = ((4 + g) ^ (r & 7)) * 8;
  const int aRowBase = (wm * 64 + r) * 64;
  const int bRowBase = (wn * 128 + r) * 64;

  // wave class for seam waits: stage order u1=Ah0,u2=Bh0,u3=Ah1,u4=Bh1
  const int cls = (wn == 1) ? 2 : (wm >> 1);  // 0:{u1,u2} 1:{u2,u3} 2:{needs u4}

  f16x8 af[4][2];
  f16x8 bf[2][2];
  f32x4 acc[4][8];
#pragma unroll
  for (int i = 0; i < 4; ++i)
#pragma unroll
    for (int j = 0; j < 8; ++j) acc[i][j] = f32x4{0.f, 0.f, 0.f, 0.f};

  // prologue: stage tile 0 into buf 0 (order u1,u2,u3,u4), class wait, barrier
  STAGE_AH(0, 0, 0)
  STAGE_BH(0, 0, 0)
  STAGE_AH(0, 1, 0)
  STAGE_BH(0, 1, 0)
  WAIT_CLASS
  __builtin_amdgcn_s_barrier();

  for (int i = 0; i < 8; ++i) {  // 2 K-tiles (BK=64) per iteration
    const int k0  = i * 128;
    const int kn1 = k0 + 64;                           // tile 2i+1 (always < 1024)
    const int kn2 = (k0 + 128 < 1024) ? k0 + 128 : 0;  // clamped junk prefetch
    TILE(0, kn1)
    TILE(1, kn2)
  }

  // epilogue: C/D layout col=lane&15, row=(lane>>4)*4+reg
  const float g2 = (EPI == 2) ? gamma[0] : 0.f;
  const int ccol  = n0 + wn * 128 + (lane & 15);
  const int crow0 = m0 + wm * 64 + (lane >> 4) * 4;
#pragma unroll
  for (int mf = 0; mf < 4; ++mf) {
#pragma unroll
    for (int reg = 0; reg < 4; ++reg) {
      const int row = crow0 + mf * 16 + reg;
      const long long rb = (long long)b * sC + (long long)row * 1024;
      const float bb = (EPI == 0) ? bias[row] : 0.f;
#pragma unroll
      for (int nf = 0; nf < 8; ++nf) {
        const int col = ccol + nf * 16;
        const float v = acc[mf][nf][reg];
        if (EPI == 0)      ((__fp16*)Cout)[rb + col] = (__fp16)(v + bb);
        else if (EPI == 1) ((float*)Cout)[rb + col] = v;
        else               ((float*)Cout)[rb + col] = g2 * v + X[rb + col];
      }
    }
  }
}

// ---------------- softmax ----------------
__global__ __launch_bounds__(256) void row_stats(const float* __restrict__ S,
                                                 float2* __restrict__ stats) {
  const int row = blockIdx.x * 4 + (threadIdx.x >> 6);
  const int lane = threadIdx.x & 63;
  const float4* rp = (const float4*)(S + (long long)row * NDIM);
  float4 v[4];
  float m = -3.4e38f;
#pragma unroll
  for (int j = 0; j < 4; j++) {
    v[j] = rp[lane + 64 * j];
    m = fmaxf(m, fmaxf(fmaxf(v[j].x, v[j].y), fmaxf(v[j].z, v[j].w)));
  }
#pragma unroll
  for (int o = 32; o; o >>= 1) m = fmaxf(m, __shfl_xor(m, o));
  float s = 0.f;
#pragma unroll
  for (int j = 0; j < 4; j++)
    s += __expf(v[j].x - m) + __expf(v[j].y - m) + __expf(v[j].z - m) + __expf(v[j].w - m);
#pragma unroll
  for (int o = 32; o; o >>= 1) s += __shfl_xor(s, o);
  if (lane == 0) stats[row] = make_float2(m, 1.f / s);
}

__global__ __launch_bounds__(256) void softmax_transpose(const float* __restrict__ S,
                                                         const float2* __restrict__ stats,
                                                         __fp16* __restrict__ attnT) {
  __shared__ __fp16 t[64][72];
  const int b = blockIdx.z;
  const int i0 = blockIdx.y * 64, j0 = blockIdx.x * 64;
  const float* Sb = S + (long long)b * NDIM * NDIM;
  const float2* st = stats + b * NDIM;
  const int tr = threadIdx.x >> 4;
  const int tc = (threadIdx.x & 15) * 4;
#pragma unroll
  for (int it = 0; it < 4; it++) {
    const int i = tr + 16 * it;
    const float4 vv = *(const float4*)&Sb[(long long)(i0 + i) * NDIM + j0 + tc];
    const float2 ms = st[i0 + i];
    t[tc + 0][i] = (__fp16)(__expf(vv.x - ms.x) * ms.y);
    t[tc + 1][i] = (__fp16)(__expf(vv.y - ms.x) * ms.y);
    t[tc + 2][i] = (__fp16)(__expf(vv.z - ms.x) * ms.y);
    t[tc + 3][i] = (__fp16)(__expf(vv.w - ms.x) * ms.y);
  }
  __syncthreads();
  __fp16* Ab = attnT + (long long)b * 3145728;
#pragma unroll
  for (int it = 0; it < 4; it++) {
    const int j = tr + 16 * it;
    f16x4 o = {t[j][tc], t[j][tc + 1], t[j][tc + 2], t[j][tc + 3]};
    *(f16x4*)&Ab[(long long)(j0 + j) * NDIM + i0 + tc] = o;
  }
}

// ---------------- launch ----------------
extern "C" void kernel_launch(void* const* d_in, const int* in_sizes, int n_in,
                              void* d_out, int out_size, void* d_ws, size_t ws_size,
                              hipStream_t stream) {
  const float* x     = (const float*)d_in[0];
  const float* Wq    = (const float*)d_in[1];
  const float* bq    = (const float*)d_in[2];
  const float* Wk    = (const float*)d_in[3];
  const float* bk    = (const float*)d_in[4];
  const float* Wv    = (const float*)d_in[5];
  const float* bv    = (const float*)d_in[6];
  const float* gamma = (const float*)d_in[7];
  char* ws = (char*)d_ws;

  __fp16* W3    = (__fp16*)(ws + OFF_W);
  float*  bias3 = (float*)(ws + OFF_BIAS);
  __fp16* xT    = (__fp16*)(ws + OFF_XT);
  float*  S     = (float*)(ws + OFF_S);
  __fp16* QKV   = (__fp16*)(ws + OFF_QKV);
  float2* stats = (float2*)(ws + OFF_STATS);
  float*  out   = (float*)d_out;

  cast_w<<<3072, 256, 0, stream>>>(Wq, Wk, Wv, W3);
  pack_bias<<<12, 256, 0, stream>>>(bq, bk, bv, bias3);
  transpose_cast_x<<<dim3(32, 32, 32), 256, 0, stream>>>(x, xT);

  // QKV[b] = W3 (3072x1024) * xT[b]^T  (+bias), fp16   [grid 4n x 12m x 32b = 1536]
  gemm256<0><<<1536, 512, 0, stream>>>(
      W3, xT, QKV, bias3, nullptr, nullptr,
      0LL, 1048576LL, 3145728LL);

  // S[b] = q[b] * k[b]^T, f32   [grid 4 x 4 x 32 = 512]
  gemm256<1><<<512, 512, 0, stream>>>(
      QKV, QKV + 1048576, S, nullptr, nullptr, nullptr,
      3145728LL, 3145728LL, 1048576LL);

  row_stats<<<8192, 256, 0, stream>>>(S, stats);
  softmax_transpose<<<dim3(16, 16, 32), 256, 0, stream>>>(S, stats, QKV);

  // out[b] = gamma * (v[b] * attnT[b]^T) + x[b], f32 -> d_out
  gemm256<2><<<512, 512, 0, stream>>>(
      QKV + 2097152, QKV, out, nullptr, x, gamma,
      3145728LL, 3145728LL, 1048576LL);
}